// Round 3
// baseline (540.025 us; speedup 1.0000x reference)
//
#include <hip/hip_runtime.h>

#define F 256
#define NODE_BUDGET 200.0f
#define COS_EPS 1e-6f

// Per-root precompute: g[b][f] = x_root*w_ego_root*w_ego_u,
// nrinv[b] = 1/max(||x_root*w_ego_root||, eps), sv[b] = x_root . w_layer_v,
// bscale[b] = budgets[b]/200
__global__ __launch_bounds__(256) void root_kernel(
    const float* __restrict__ x,
    const float* __restrict__ w_ego_root,
    const float* __restrict__ w_ego_u,
    const float* __restrict__ w_layer_v,
    const float* __restrict__ budgets,
    const int* __restrict__ batch_nodes,
    float* __restrict__ g, float* __restrict__ nrinv,
    float* __restrict__ sv, float* __restrict__ bscale)
{
    __shared__ float red[2][4];
    int b = blockIdx.x;
    int f = threadIdx.x;  // F == 256 == blockDim.x
    int root = batch_nodes[b];
    float xf = x[(size_t)root * F + f];
    float hr = xf * w_ego_root[f];
    g[(size_t)b * F + f] = hr * w_ego_u[f];
    float a = hr * hr;
    float c = xf * w_layer_v[f];
    #pragma unroll
    for (int off = 32; off; off >>= 1) {
        a += __shfl_xor(a, off);
        c += __shfl_xor(c, off);
    }
    int lane = f & 63, wv = f >> 6;
    if (lane == 0) { red[0][wv] = a; red[1][wv] = c; }
    __syncthreads();
    if (f == 0) {
        float as = red[0][0] + red[0][1] + red[0][2] + red[0][3];
        float cs = red[1][0] + red[1][1] + red[1][2] + red[1][3];
        nrinv[b] = 1.0f / fmaxf(sqrtf(as), COS_EPS);
        sv[b] = cs;
        bscale[b] = budgets[b] * (1.0f / NODE_BUDGET);
    }
}

// Build per-node candidate linked lists: head[u] -> chain of m via next[m].
// atomicExch order is nondeterministic but per-m outputs are order-independent.
__global__ __launch_bounds__(256) void build_lists_kernel(
    const int* __restrict__ u_ids, int* __restrict__ head,
    int* __restrict__ next, int M)
{
    int i = blockIdx.x * 256 + threadIdx.x;
    if (i >= M) return;
    int u = u_ids[i];
    next[i] = atomicExch(&head[u], i);
}

// agg[dst] += sv[src] over E edges (dst ~uniform over M=500k -> low contention)
__global__ __launch_bounds__(256) void edge_kernel(
    const int* __restrict__ edge_src, const int* __restrict__ edge_dst,
    const float* __restrict__ sv, float* __restrict__ agg, int E)
{
    int i = blockIdx.x * 256 + threadIdx.x;
    int stride = gridDim.x * 256;
    for (; i < E; i += stride)
        atomicAdd(&agg[edge_dst[i]], sv[edge_src[i]]);
}

// ONE WAVE (64 lanes) PER NODE: x row = exactly one float4 per lane (256 f32),
// loaded in a single instruction. Chain walk is wave-uniform (zero divergence,
// no inter-chain lockstep waste), 2-deep software pipelined: element i+1's
// next/batch_ptr/agg/g-row loads issue before element i's reduce, collapsing
// the two dependent latencies per element into ~one.
__global__ __launch_bounds__(256) void cand_wave_kernel(
    const float* __restrict__ x,
    const int* __restrict__ head, const int* __restrict__ next,
    const int* __restrict__ batch_ptr,
    const float* __restrict__ g, const float* __restrict__ nrinv,
    const float* __restrict__ bscale, const float* __restrict__ agg,
    const float* __restrict__ w_ego_u, const float* __restrict__ w_layer_u,
    const float* __restrict__ n_imp,
    float* __restrict__ p_out, int N)
{
    int lane = threadIdx.x & 63;
    int n = blockIdx.x * 4 + (threadIdx.x >> 6);
    if (n >= N) return;
    int m = head[n];
    if (m < 0) return;            // 8% of nodes: no candidates, no x load

    float4 xv = ((const float4*)(x + (size_t)n * F))[lane];
    float4 wu = ((const float4*)w_ego_u)[lane];    // 1KB, L1-broadcast
    float4 wl = ((const float4*)w_layer_u)[lane];  // 1KB, L1-broadcast
    float h0 = xv.x*wu.x, h1 = xv.y*wu.y, h2 = xv.z*wu.z, h3 = xv.w*wu.w;
    float a2 = h0*h0 + h1*h1 + h2*h2 + h3*h3;
    float su = xv.x*wl.x + xv.y*wl.y + xv.z*wl.z + xv.w*wl.w;
    #pragma unroll
    for (int off = 32; off; off >>= 1) {
        a2 += __shfl_xor(a2, off);
        su += __shfl_xor(su, off);
    }
    float inv_nu = 1.0f / fmaxf(sqrtf(a2), COS_EPS);
    float imp = n_imp[n];

    // prologue of the pipelined walk
    int b0 = batch_ptr[m];
    float ag0 = agg[m];
    int m1 = next[m];
    float4 g0 = ((const float4*)(g + (size_t)b0 * F))[lane];  // L2-resident (1MB)

    while (m >= 0) {
        // prefetch element i+1 (wave-uniform branch)
        int m2 = -1, b1 = 0;
        float ag1 = 0.0f;
        float4 g1 = make_float4(0.f, 0.f, 0.f, 0.f);
        if (m1 >= 0) {
            b1 = batch_ptr[m1];
            ag1 = agg[m1];
            m2 = next[m1];
            g1 = ((const float4*)(g + (size_t)b1 * F))[lane];
        }
        // compute element i
        float acc = xv.x*g0.x + xv.y*g0.y + xv.z*g0.z + xv.w*g0.w;
        #pragma unroll
        for (int off = 32; off; off >>= 1)
            acc += __shfl_xor(acc, off);
        float ego = acc * inv_nu * nrinv[b0];
        float layer = tanhf(ag0 + su);
        float p = (0.5f * ego + 0.5f * layer) * imp * bscale[b0];
        if (lane == 0) p_out[m] = p;
        // rotate pipeline
        m = m1; b0 = b1; ag0 = ag1; g0 = g1; m1 = m2;
    }
}

// Fused segment-max + normalize: batch_ptr sorted -> contiguous segments.
// One block per b; binary-search bounds; max-reduce; normalize in place.
__global__ __launch_bounds__(256) void seg_norm_kernel(
    const int* __restrict__ batch_ptr, float* __restrict__ out, int M)
{
    int b = blockIdx.x;
    int lo = 0, hi = M;
    while (lo < hi) { int mid = (lo + hi) >> 1; if (batch_ptr[mid] < b) lo = mid + 1; else hi = mid; }
    int start = lo;
    hi = M;
    while (lo < hi) { int mid = (lo + hi) >> 1; if (batch_ptr[mid] <= b) lo = mid + 1; else hi = mid; }
    int end = lo;
    float mx = -INFINITY;
    for (int i = start + threadIdx.x; i < end; i += 256)
        mx = fmaxf(mx, out[i]);
    #pragma unroll
    for (int off = 32; off; off >>= 1)
        mx = fmaxf(mx, __shfl_xor(mx, off));
    __shared__ float red[4];
    __shared__ float s_pn;
    int lane = threadIdx.x & 63, wv = threadIdx.x >> 6;
    if (lane == 0) red[wv] = mx;
    __syncthreads();
    if (threadIdx.x == 0)
        s_pn = fmaxf(fmaxf(red[0], red[1]), fmaxf(red[2], red[3]));
    __syncthreads();
    float pn = s_pn;
    for (int i = start + threadIdx.x; i < end; i += 256) {
        float v = out[i] / pn + 1.0f;
        if (isnan(v)) v = 0.0f;
        else if (isinf(v)) v = 1.0f;
        out[i] = fminf(fmaxf(v, 1e-5f), 1.0f);
    }
}

extern "C" void kernel_launch(void* const* d_in, const int* in_sizes, int n_in,
                              void* d_out, int out_size, void* d_ws, size_t ws_size,
                              hipStream_t stream) {
    const float* x          = (const float*)d_in[0];
    const float* w_ego_root = (const float*)d_in[1];
    const float* w_ego_u    = (const float*)d_in[2];
    const float* w_layer_v  = (const float*)d_in[3];
    const float* w_layer_u  = (const float*)d_in[4];
    const float* n_imp      = (const float*)d_in[5];
    const float* budgets    = (const float*)d_in[6];
    const int* batch_nodes = (const int*)d_in[7];
    const int* u_ids       = (const int*)d_in[8];
    const int* batch_ptr   = (const int*)d_in[9];
    const int* edge_src    = (const int*)d_in[10];
    const int* edge_dst    = (const int*)d_in[11];
    float* out = (float*)d_out;

    int N = in_sizes[5];
    int B = in_sizes[7];
    int M = in_sizes[8];
    int E = in_sizes[10];

    float* ws = (float*)d_ws;
    size_t off = 0;
    float* agg = ws + off;                          off += (size_t)((M + 3) & ~3);
    size_t zero_bytes = off * sizeof(float);        // agg needs zero-init
    float* g       = ws + off;                      off += (size_t)B * F;
    float* nrinv   = ws + off;                      off += (size_t)((B + 3) & ~3);
    float* sv      = ws + off;                      off += (size_t)((B + 3) & ~3);
    float* bscale  = ws + off;                      off += (size_t)((B + 3) & ~3);
    int* head      = (int*)(ws + off);              off += (size_t)((N + 3) & ~3);
    int* next      = (int*)(ws + off);              off += (size_t)((M + 3) & ~3);

    hipMemsetAsync(d_ws, 0, zero_bytes, stream);
    hipMemsetAsync(head, 0xFF, (size_t)N * sizeof(int), stream);  // head = -1

    root_kernel<<<B, 256, 0, stream>>>(x, w_ego_root, w_ego_u, w_layer_v,
                                       budgets, batch_nodes, g, nrinv, sv, bscale);
    build_lists_kernel<<<(M + 255) / 256, 256, 0, stream>>>(u_ids, head, next, M);
    edge_kernel<<<2048, 256, 0, stream>>>(edge_src, edge_dst, sv, agg, E);
    cand_wave_kernel<<<(N + 3) / 4, 256, 0, stream>>>(x, head, next, batch_ptr,
                                                      g, nrinv, bscale, agg,
                                                      w_ego_u, w_layer_u, n_imp,
                                                      out, N);
    seg_norm_kernel<<<B, 256, 0, stream>>>(batch_ptr, out, M);
}